// Round 6
// baseline (257.267 us; speedup 1.0000x reference)
//
#include <hip/hip_runtime.h>
#include <cstdint>

#define D 128
#define T 64
#define B 512
#define EPSF 1e-5f

// wave-uniform lane broadcast via v_readlane (no LDS/ds_bpermute)
__device__ __forceinline__ float lane_bcast(float x, int l) {
    return __int_as_float(__builtin_amdgcn_readlane(__float_as_int(x), l));
}

// ---------------------------------------------------------------------------
// prep: vT[k*D+i] = v[i][k] = W[i][k]/max(norm_i,1e-12); vd[i]=v[i][i]; absb=|b|
// ---------------------------------------------------------------------------
__global__ __launch_bounds__(64) void prep_kernel(const float* __restrict__ W,
                                                  const float* __restrict__ b,
                                                  float* __restrict__ vT,
                                                  float* __restrict__ vd,
                                                  float* __restrict__ absb) {
    const int i = blockIdx.x;
    const int l = threadIdx.x;
    float w0 = W[i * D + l];
    float w1 = W[i * D + l + 64];
    float p = w0 * w0 + w1 * w1;
#pragma unroll
    for (int off = 32; off; off >>= 1) p += __shfl_xor(p, off);
    float norm = sqrtf(p);
    float scale = norm > 1e-12f ? norm : 1e-12f;
    float v0 = w0 / scale;
    float v1 = w1 / scale;
    vT[l * D + i] = v0;
    vT[(l + 64) * D + i] = v1;
    if (i < 64) {
        if (l == i) vd[i] = v0;
    } else {
        if (l == i - 64) vd[i] = v1;
    }
    if (i == 0) {
        absb[l] = fabsf(b[l]);
        absb[l + 64] = fabsf(b[l + 64]);
    }
}

// ---------------------------------------------------------------------------
// main RNN kernel. One wave per batch column; lane owns rows (lane, lane+64).
// NO barriers in the t-loop (round-1: per-step vmcnt(0) drains cost −62%).
// Matvec reads v from AGPR-pinned registers (round-4: zero LDS traffic).
//
// Round-4 lesson: removing ALL matvec LDS latency saved only ~130cy/step ->
// the ~4000cy/step residual is the CORRECTION phase: serial probe/sweep
// iterations each carrying ballot->ffs->readlane->ds_read(~120cy)->fma with
// 1 wave/SIMD (nothing hides the latency). Fix: the candidate sequence is
// determined by the ENTRY masks and v is constant -> prefetch up to 8
// violator columns into registers with back-to-back ds_reads (ONE latency,
// overlapped with the dl/dh divides), then:
//  - probe: pure ALU+ballot per candidate (exact same order/arithmetic)
//  - sweep phase 1: statically unrolled slot consumption while the actual
//    next violator matches the prefetched sequence; ANY deviation (new
//    violator / stale slot handling / slots exhausted) falls back to the
//    verbatim original loop (phase 2). Bit-identical semantics.
//
// vsh (swizzled column layout) stays in LDS for runtime-j column access:
//   vsh[k*128 + (i ^ ((k&7)<<2))] = v[i][k]
//  - row reads (probe/sweep/slots; fixed k, i=lane): 2-way bank alias = free
//  - column reads (parallel judge, ~1% of steps): b128, structural 8/bank
// ---------------------------------------------------------------------------
__global__ __launch_bounds__(128, 1) void rnn_kernel(const float* __restrict__ input,
                                                     const float* __restrict__ target,
                                                     const float* __restrict__ returns,
                                                     const float* __restrict__ vTg,
                                                     const float* __restrict__ vdg,
                                                     const float* __restrict__ absbg,
                                                     float* __restrict__ out) {
    __shared__ float vsh[D * D];   // exactly 64 KB

    const int tid = threadIdx.x;
    // cooperative swizzled load of vT (plain layout in ws -> swizzled LDS)
    {
        const float4* src = (const float4*)vTg;
        float4* dst = (float4*)vsh;
#pragma unroll
        for (int c = 0; c < 32; ++c) {
            int f = c * 128 + tid;          // source float4 index
            int k = f >> 5;                 // row k of vT
            int i = (f & 31) << 2;          // starting i of this float4
            int ck = (k & 7) << 2;
            int d4 = k * 32 + (((i ^ ck)) >> 2);
            dst[d4] = src[f];
        }
    }
    __syncthreads();

    const int w = tid >> 6;
    const int lane = tid & 63;
    const int b = blockIdx.x * 2 + w;
    const int rlo = lane, rhi = lane + 64;

    const float tgt_lo = target[rlo], tgt_hi = target[rhi];
    const float a_lo = absbg[rlo], a_hi = absbg[rhi];
    const float aeps_lo = a_lo + EPSF, aeps_hi = a_hi + EPSF;
    const float vd_lo = vdg[rlo], vd_hi = vdg[rhi];
    const float rvd_lo = 1.0f / vd_lo, rvd_hi = 1.0f / vd_hi;

    // row-read xor bases: vsh[k*128 + ax[k&7]] (+64 for hi row)
    int ax[8];
#pragma unroll
    for (int c = 0; c < 8; ++c) ax[c] = rlo ^ (c << 2);

    // ---- register-resident v rows, PINNED in AGPRs (one-time LDS read;
    //      "+a" asm result is non-rematerializable -> stays resident) ----
    float vl[D], vh[D];
#pragma unroll
    for (int k = 0; k < D; ++k) {
        int base = k * 128 + ax[k & 7];
        vl[k] = vsh[base];
        vh[k] = vsh[base + 64];
        asm volatile("" : "+a"(vl[k]), "+a"(vh[k]));
    }

    // parallel-judge column bases: candidate j=lane reads float4 at
    // Abase[c] + 32*a  (logical i0 = a*32 + c*4); candidate lane+64 at +8192
    const int cj = (lane & 7) << 2;
    int Abase[8];
#pragma unroll
    for (int c = 0; c < 8; ++c) Abase[c] = lane * 128 + ((c << 2) ^ cj);

    float h_lo = input[rlo * T * B + b];
    float h_hi = input[rhi * T * B + b];
    out[rlo * T * B + b] = h_lo;
    out[rhi * T * B + b] = h_hi;

    float r_lo = returns[rlo * T * B + b];
    float r_hi = returns[rhi * T * B + b];

    for (int t = 1; t < T; ++t) {
        // ---- adj = h*(1+r)/(1 + sum(h*r)) ----
        float num_lo = h_lo * (1.0f + r_lo);
        float num_hi = h_hi * (1.0f + r_hi);
        float p = h_lo * r_lo + h_hi * r_hi;
#pragma unroll
        for (int off = 32; off; off >>= 1) p += __shfl_xor(p, off);
        float den = 1.0f + p;
        float adj_lo = num_lo / den;
        float adj_hi = num_hi / den;

        if (t < T - 1) {
            r_lo = returns[rlo * T * B + t * B + b];
            r_hi = returns[rhi * T * B + t * B + b];
        }

        const float x_lo = adj_lo - tgt_lo;
        const float x_hi = adj_hi - tgt_hi;

        // ---- s = v @ (adj - pi_bar): readlane broadcast + AGPR-resident v.
        //      k ascending, single accumulator per row -> bit-identical to
        //      round-0. Zero LDS traffic. ----
        float s_lo = 0.0f, s_hi = 0.0f;
#pragma unroll
        for (int k = 0; k < 64; ++k) {
            float xb = lane_bcast(x_lo, k);
            s_lo = fmaf(vl[k], xb, s_lo);
            s_hi = fmaf(vh[k], xb, s_hi);
        }
#pragma unroll
        for (int k = 0; k < 64; ++k) {
            float xb = lane_bcast(x_hi, k);
            s_lo = fmaf(vl[64 + k], xb, s_lo);
            s_hi = fmaf(vh[64 + k], xb, s_hi);
        }

        h_lo = adj_lo;
        h_hi = adj_hi;

        // ================= correction ======================================
        bool viol_lo = (s_lo > a_lo) || (s_lo < -a_lo);
        bool viol_hi = (s_hi > a_hi) || (s_hi < -a_hi);
        uint64_t mlo = __ballot(viol_lo);
        uint64_t mhi = __ballot(viol_hi);

        if ((mlo | mhi) != 0ull) {
            // ---- prefetch up to 8 violator columns (ascending lo-then-hi;
            //      exactly the probe/sweep visit order). All ds_reads issue
            //      back-to-back -> one latency, overlapped with the divides
            //      below. v is constant, so prefetched columns are valid
            //      regardless of which js actually get visited. ----
            int js[8];
            float cl[8], ch[8];
            {
                uint64_t p_lo = mlo, p_hi = mhi;
#pragma unroll
                for (int n = 0; n < 8; ++n) {
                    int j = -1;
                    if (p_lo) { j = (int)__ffsll((unsigned long long)p_lo) - 1; p_lo &= p_lo - 1; }
                    else if (p_hi) { j = 64 + (int)__ffsll((unsigned long long)p_hi) - 1; p_hi &= p_hi - 1; }
                    js[n] = j;
                    if (j >= 0) {
                        int base = (j << 7) + (rlo ^ ((j & 7) << 2));
                        cl[n] = vsh[base];
                        ch[n] = vsh[base + 64];
                    } else { cl[n] = 0.0f; ch[n] = 0.0f; }
                }
            }

            // per-lane deltas (reference lam formulas, IEEE div)
            float dl = 0.0f, dh = 0.0f;
            if (s_lo > a_lo) dl = (a_lo - s_lo) / vd_lo;
            else if (s_lo < -a_lo) dl = (-a_lo - s_lo) / vd_lo;
            if (s_hi > a_hi) dh = (a_hi - s_hi) / vd_hi;
            else if (s_hi < -a_hi) dh = (-a_hi - s_hi) / vd_hi;

            int V = __popcll(mlo) + __popcll(mhi);
            bool judge;

            if (V <= 8) {
                // q0: all strictly inside a+eps and (V<64 so) a zero-delta
                // column exists
                bool in_lo = (s_lo < aeps_lo) && (s_lo > -aeps_lo);
                bool in_hi = (s_hi < aeps_hi) && (s_hi > -aeps_hi);
                judge = (__ballot(in_lo && in_hi) == ~0ull);
                if (!judge) {
                    // slot-based probe: same candidate order & arithmetic as
                    // the original serial loop, LDS latency already paid.
                    bool done = false;
#pragma unroll
                    for (int n = 0; n < 8; ++n) {
                        if (!done && js[n] >= 0) {
                            int j = js[n];
                            float dj = lane_bcast((j < 64) ? dl : dh, j & 63);
                            float n_lo = fmaf(cl[n], dj, s_lo);
                            float n_hi = fmaf(ch[n], dj, s_hi);
                            bool pl = (n_lo < aeps_lo) && (n_lo > -aeps_lo);
                            bool ph = (n_hi < aeps_hi) && (n_hi > -aeps_hi);
                            if (__ballot(pl && ph) == ~0ull) { judge = true; done = true; }
                        }
                    }
                }
            } else {
                // ---- parallel judge: lane tests candidates j=lane, lane+64.
                // Covers d=0 candidates (q0) uniformly.
                float m1 = -1.0f, m2 = -1.0f;   // only the sign of max matters
#pragma unroll
                for (int a = 0; a < 4; ++a) {
#pragma unroll
                    for (int c = 0; c < 8; ++c) {
                        const int i0 = a * 32 + c * 4;
                        const float* p1 = &vsh[Abase[c] + 32 * a];
                        float4 c1 = *(const float4*)p1;
                        float4 c2 = *(const float4*)(p1 + 8192);
#pragma unroll
                        for (int e = 0; e < 4; ++e) {
                            const int i = i0 + e;
                            float sv = (i < 64) ? lane_bcast(s_lo, i)
                                                : lane_bcast(s_hi, i - 64);
                            float ae = (i < 64) ? lane_bcast(aeps_lo, i)
                                                : lane_bcast(aeps_hi, i - 64);
                            float f1 = ((const float*)&c1)[e];
                            float f2 = ((const float*)&c2)[e];
                            m1 = fmaxf(m1, fabsf(fmaf(f1, dl, sv)) - ae);
                            m2 = fmaxf(m2, fabsf(fmaf(f2, dh, sv)) - ae);
                        }
                    }
                }
                judge = ((__ballot(m1 < 0.0f) | __ballot(m2 < 0.0f)) != 0ull);
            }

            if (judge) {
                // ---- Gauss-Seidel sweep (ascending j, violators only) ----
                uint64_t rem_lo = ~0ull, rem_hi = ~0ull;

                // phase 1: consume prefetched slots while the actual next
                // violator matches the prefetched sequence. Identical visit
                // order / delta arithmetic to the original loop; only the
                // v-column source differs (same values, from registers).
                bool fin = false;    // no violators remain
                bool fall = false;   // deviation -> phase 2 handles the rest
#pragma unroll
                for (int n = 0; n < 8; ++n) {
                    if (!fall && !fin && js[n] >= 0) {
                        uint64_t m1b = __ballot((s_lo > a_lo) || (s_lo < -a_lo)) & rem_lo;
                        uint64_t m2b = __ballot((s_hi > a_hi) || (s_hi < -a_hi)) & rem_hi;
                        int j = -1;
                        if (m1b) j = (int)__ffsll((unsigned long long)m1b) - 1;
                        else if (m2b) j = 64 + (int)__ffsll((unsigned long long)m2b) - 1;
                        if (j < 0) {
                            fin = true;
                        } else if (j < js[n]) {
                            fall = true;            // new violator, not prefetched
                        } else if (j == js[n]) {    // (j > js[n]: stale slot, skip)
                            float dl2 = (s_lo > a_lo) ? (a_lo - s_lo) * rvd_lo
                                       : ((s_lo < -a_lo) ? (-a_lo - s_lo) * rvd_lo : 0.0f);
                            float dh2 = (s_hi > a_hi) ? (a_hi - s_hi) * rvd_hi
                                       : ((s_hi < -a_hi) ? (-a_hi - s_hi) * rvd_hi : 0.0f);
                            float dj = lane_bcast((j < 64) ? dl2 : dh2, j & 63);
                            if (lane == (j & 63)) {
                                if (j < 64) h_lo += dj; else h_hi += dj;
                            }
                            s_lo = fmaf(cl[n], dj, s_lo);
                            s_hi = fmaf(ch[n], dj, s_hi);
                            if (j < 64) {
                                rem_lo = (j == 63) ? 0ull : (~0ull << (j + 1));
                            } else {
                                rem_lo = 0ull;
                                rem_hi = (j == 127) ? 0ull : (~0ull << (j - 63));
                            }
                        }
                    }
                }

                // phase 2: verbatim original loop (handles fall-back, V>8
                // tail, and any new violators). No-op if fin.
                if (!fin) {
                    while (true) {
                        uint64_t m1b = __ballot((s_lo > a_lo) || (s_lo < -a_lo)) & rem_lo;
                        uint64_t m2b = __ballot((s_hi > a_hi) || (s_hi < -a_hi)) & rem_hi;
                        int j;
                        if (m1b) {
                            int jl = (int)__ffsll((unsigned long long)m1b) - 1;
                            j = jl;
                            rem_lo = (jl == 63) ? 0ull : (~0ull << (jl + 1));
                        } else if (m2b) {
                            int jh = (int)__ffsll((unsigned long long)m2b) - 1;
                            j = 64 + jh;
                            rem_lo = 0ull;
                            rem_hi = (jh == 63) ? 0ull : (~0ull << (jh + 1));
                        } else {
                            break;
                        }
                        float dl2 = (s_lo > a_lo) ? (a_lo - s_lo) * rvd_lo
                                   : ((s_lo < -a_lo) ? (-a_lo - s_lo) * rvd_lo : 0.0f);
                        float dh2 = (s_hi > a_hi) ? (a_hi - s_hi) * rvd_hi
                                   : ((s_hi < -a_hi) ? (-a_hi - s_hi) * rvd_hi : 0.0f);
                        float srcv = (j < 64) ? dl2 : dh2;
                        float dj = lane_bcast(srcv, j & 63);
                        if (lane == (j & 63)) {
                            if (j < 64) h_lo += dj; else h_hi += dj;
                        }
                        int cjj = (j & 7) << 2;
                        int base = j * 128 + (rlo ^ cjj);
                        s_lo = fmaf(vsh[base], dj, s_lo);
                        s_hi = fmaf(vsh[base + 64], dj, s_hi);
                    }
                }
            } else {
                // ---- bisection between pi_bar (s=0) and adj (s), s-space ----
                float hin_lo = tgt_lo, hin_hi = tgt_hi;
                float sin_lo = 0.0f, sin_hi = 0.0f;
                float hout_lo = h_lo, hout_hi = h_hi;
                float sout_lo = s_lo, sout_hi = s_hi;
                float hm_lo = 0.0f, hm_hi = 0.0f;
#pragma unroll
                for (int it = 0; it < 10; ++it) {
                    hm_lo = hin_lo + (hout_lo - hin_lo) * 0.5f;
                    hm_hi = hin_hi + (hout_hi - hin_hi) * 0.5f;
                    float sm_lo = sin_lo + (sout_lo - sin_lo) * 0.5f;
                    float sm_hi = sin_hi + (sout_hi - sin_hi) * 0.5f;
                    bool pl = (sm_lo <= aeps_lo) && (sm_lo >= -aeps_lo);
                    bool ph = (sm_hi <= aeps_hi) && (sm_hi >= -aeps_hi);
                    bool inside = (__ballot(pl && ph) == ~0ull);
                    if (inside) {
                        hin_lo = hm_lo; hin_hi = hm_hi;
                        sin_lo = sm_lo; sin_hi = sm_hi;
                    } else {
                        hout_lo = hm_lo; hout_hi = hm_hi;
                        sout_lo = sm_lo; sout_hi = sm_hi;
                    }
                }
                h_lo = hm_lo;
                h_hi = hm_hi;
            }
        }
        // else: no violators -> judge=1, sweep is a no-op, h unchanged

        out[rlo * T * B + t * B + b] = h_lo;
        out[rhi * T * B + t * B + b] = h_hi;
    }

    out[D * T * B + rlo * B + b] = h_lo;
    out[D * T * B + rhi * B + b] = h_hi;
}

extern "C" void kernel_launch(void* const* d_in, const int* in_sizes, int n_in,
                              void* d_out, int out_size, void* d_ws, size_t ws_size,
                              hipStream_t stream) {
    const float* input   = (const float*)d_in[0];
    const float* target  = (const float*)d_in[1];
    const float* returns = (const float*)d_in[2];
    // d_in[3] = hidden (unused by the reference)
    const float* W = (const float*)d_in[4];
    const float* b = (const float*)d_in[5];
    float* out = (float*)d_out;

    float* vT   = (float*)d_ws;            // 16384 floats
    float* vd   = vT + D * D;              // 128 floats
    float* absb = vd + D;                  // 128 floats

    prep_kernel<<<D, 64, 0, stream>>>(W, b, vT, vd, absb);
    rnn_kernel<<<B / 2, 128, 0, stream>>>(input, target, returns, vT, vd, absb, out);
}

// Round 7
// 216.445 us; speedup vs baseline: 1.1886x; 1.1886x over previous
//
#include <hip/hip_runtime.h>
#include <cstdint>

#define D 128
#define T 64
#define B 512
#define EPSF 1e-5f

// wave-uniform lane broadcast via v_readlane (no LDS/ds_bpermute)
__device__ __forceinline__ float lane_bcast(float x, int l) {
    return __int_as_float(__builtin_amdgcn_readlane(__float_as_int(x), l));
}

// ---------------------------------------------------------------------------
// prep: vT[k*D+i] = v[i][k] = W[i][k]/max(norm_i,1e-12); vd[i]=v[i][i]; absb=|b|
// ---------------------------------------------------------------------------
__global__ __launch_bounds__(64) void prep_kernel(const float* __restrict__ W,
                                                  const float* __restrict__ b,
                                                  float* __restrict__ vT,
                                                  float* __restrict__ vd,
                                                  float* __restrict__ absb) {
    const int i = blockIdx.x;
    const int l = threadIdx.x;
    float w0 = W[i * D + l];
    float w1 = W[i * D + l + 64];
    float p = w0 * w0 + w1 * w1;
#pragma unroll
    for (int off = 32; off; off >>= 1) p += __shfl_xor(p, off);
    float norm = sqrtf(p);
    float scale = norm > 1e-12f ? norm : 1e-12f;
    float v0 = w0 / scale;
    float v1 = w1 / scale;
    vT[l * D + i] = v0;
    vT[(l + 64) * D + i] = v1;
    if (i < 64) {
        if (l == i) vd[i] = v0;
    } else {
        if (l == i - 64) vd[i] = v1;
    }
    if (i == 0) {
        absb[l] = fabsf(b[l]);
        absb[l + 64] = fabsf(b[l + 64]);
    }
}

// ---------------------------------------------------------------------------
// main RNN kernel. One wave per batch column; lane owns rows (lane, lane+64).
// NO barriers in the t-loop (round-1: per-step vmcnt(0) drains cost −62%).
// Matvec reads v from AGPR-pinned registers (round-4). Round-6's prefetch/
// slot machinery REVERTED (+44us: overhead on every step, target wasn't hot).
//
// Round-7 theory: SQ_LDS_BANK_CONFLICT says nothing about parallel-judge
// frequency (its b128 column reads are structural-minimum, not conflicts),
// so the V>8 judge may run on a large fraction of steps at ~1200 VALU inst
// per invocation — the missing ~1200cy/step of correction issue. Changes:
//  (a) s/aeps broadcasts in the judge: uniform-address ds_read_b128 (HW
//      broadcast) instead of 256 v_readlane per invocation. aeps staged in
//      LDS once at init; s staged (2 ds_write) at correction entry, RAW
//      latency hidden under the q0/divide code.
//  (b) early-all-dead exit: if after a 32-element block every candidate has
//      m>0, final judge is provably false -> break. Exact same judge bool.
//
// vsh (swizzled column layout) in LDS for runtime-j column access:
//   vsh[k*128 + (i ^ ((k&7)<<2))] = v[i][k]
//  - row reads (probe/sweep; fixed k, i=lane): 2-way bank alias = free
//  - column reads (parallel judge): b128, structural 8/bank minimum
// ---------------------------------------------------------------------------
__global__ __launch_bounds__(128, 1) void rnn_kernel(const float* __restrict__ input,
                                                     const float* __restrict__ target,
                                                     const float* __restrict__ returns,
                                                     const float* __restrict__ vTg,
                                                     const float* __restrict__ vdg,
                                                     const float* __restrict__ absbg,
                                                     float* __restrict__ out) {
    __shared__ float vsh[D * D];                    // 64 KB
    __shared__ __align__(16) float aeps_arr[D];     // judge broadcast (const)
    __shared__ __align__(16) float sstage[2][D];    // judge broadcast (per wave)

    const int tid = threadIdx.x;
    // cooperative swizzled load of vT (plain layout in ws -> swizzled LDS)
    {
        const float4* src = (const float4*)vTg;
        float4* dst = (float4*)vsh;
#pragma unroll
        for (int c = 0; c < 32; ++c) {
            int f = c * 128 + tid;          // source float4 index
            int k = f >> 5;                 // row k of vT
            int i = (f & 31) << 2;          // starting i of this float4
            int ck = (k & 7) << 2;
            int d4 = k * 32 + (((i ^ ck)) >> 2);
            dst[d4] = src[f];
        }
    }
    aeps_arr[tid] = absbg[tid] + EPSF;      // tid covers 0..127 = D
    __syncthreads();

    const int w = tid >> 6;
    const int lane = tid & 63;
    const int b = blockIdx.x * 2 + w;
    const int rlo = lane, rhi = lane + 64;

    const float tgt_lo = target[rlo], tgt_hi = target[rhi];
    const float a_lo = absbg[rlo], a_hi = absbg[rhi];
    const float aeps_lo = a_lo + EPSF, aeps_hi = a_hi + EPSF;
    const float vd_lo = vdg[rlo], vd_hi = vdg[rhi];
    const float rvd_lo = 1.0f / vd_lo, rvd_hi = 1.0f / vd_hi;

    // row-read xor bases: vsh[k*128 + ax[k&7]] (+64 for hi row)
    int ax[8];
#pragma unroll
    for (int c = 0; c < 8; ++c) ax[c] = rlo ^ (c << 2);

    // ---- register-resident v rows, PINNED in AGPRs (one-time LDS read;
    //      "+a" asm result is non-rematerializable -> stays resident) ----
    float vl[D], vh[D];
#pragma unroll
    for (int k = 0; k < D; ++k) {
        int base = k * 128 + ax[k & 7];
        vl[k] = vsh[base];
        vh[k] = vsh[base + 64];
        asm volatile("" : "+a"(vl[k]), "+a"(vh[k]));
    }

    // parallel-judge column bases: candidate j=lane reads float4 at
    // Abase[c] + 32*a  (logical i0 = a*32 + c*4); candidate lane+64 at +8192
    const int cj = (lane & 7) << 2;
    int Abase[8];
#pragma unroll
    for (int c = 0; c < 8; ++c) Abase[c] = lane * 128 + ((c << 2) ^ cj);

    float h_lo = input[rlo * T * B + b];
    float h_hi = input[rhi * T * B + b];
    out[rlo * T * B + b] = h_lo;
    out[rhi * T * B + b] = h_hi;

    float r_lo = returns[rlo * T * B + b];
    float r_hi = returns[rhi * T * B + b];

    for (int t = 1; t < T; ++t) {
        // ---- adj = h*(1+r)/(1 + sum(h*r)) ----
        float num_lo = h_lo * (1.0f + r_lo);
        float num_hi = h_hi * (1.0f + r_hi);
        float p = h_lo * r_lo + h_hi * r_hi;
#pragma unroll
        for (int off = 32; off; off >>= 1) p += __shfl_xor(p, off);
        float den = 1.0f + p;
        float adj_lo = num_lo / den;
        float adj_hi = num_hi / den;

        if (t < T - 1) {
            r_lo = returns[rlo * T * B + t * B + b];
            r_hi = returns[rhi * T * B + t * B + b];
        }

        const float x_lo = adj_lo - tgt_lo;
        const float x_hi = adj_hi - tgt_hi;

        // ---- s = v @ (adj - pi_bar): readlane broadcast + AGPR-resident v.
        //      k ascending, single accumulator per row -> bit-identical to
        //      round-0. Zero LDS traffic. ----
        float s_lo = 0.0f, s_hi = 0.0f;
#pragma unroll
        for (int k = 0; k < 64; ++k) {
            float xb = lane_bcast(x_lo, k);
            s_lo = fmaf(vl[k], xb, s_lo);
            s_hi = fmaf(vh[k], xb, s_hi);
        }
#pragma unroll
        for (int k = 0; k < 64; ++k) {
            float xb = lane_bcast(x_hi, k);
            s_lo = fmaf(vl[64 + k], xb, s_lo);
            s_hi = fmaf(vh[64 + k], xb, s_hi);
        }

        h_lo = adj_lo;
        h_hi = adj_hi;

        // ================= correction ======================================
        bool viol_lo = (s_lo > a_lo) || (s_lo < -a_lo);
        bool viol_hi = (s_hi > a_hi) || (s_hi < -a_hi);
        uint64_t mlo = __ballot(viol_lo);
        uint64_t mhi = __ballot(viol_hi);

        if ((mlo | mhi) != 0ull) {
            // stage s for uniform-broadcast reads in the judge (wave-private;
            // RAW latency hidden under q0/divides below)
            sstage[w][rlo] = s_lo;
            sstage[w][rhi] = s_hi;

            // per-lane deltas (reference lam formulas, IEEE div)
            float dl = 0.0f, dh = 0.0f;
            if (s_lo > a_lo) dl = (a_lo - s_lo) / vd_lo;
            else if (s_lo < -a_lo) dl = (-a_lo - s_lo) / vd_lo;
            if (s_hi > a_hi) dh = (a_hi - s_hi) / vd_hi;
            else if (s_hi < -a_hi) dh = (-a_hi - s_hi) / vd_hi;

            int V = __popcll(mlo) + __popcll(mhi);
            bool judge;

            if (V <= 8) {
                // q0: all strictly inside a+eps and (V<64 so) a zero-delta
                // column exists
                bool in_lo = (s_lo < aeps_lo) && (s_lo > -aeps_lo);
                bool in_hi = (s_hi < aeps_hi) && (s_hi > -aeps_hi);
                judge = (__ballot(in_lo && in_hi) == ~0ull);
                if (!judge) {
                    uint64_t t_mlo = mlo, t_mhi = mhi;
                    while (t_mlo | t_mhi) {
                        int j;
                        float dj;
                        if (t_mlo) {
                            int jl = (int)__ffsll((unsigned long long)t_mlo) - 1;
                            t_mlo &= t_mlo - 1;
                            j = jl;
                            dj = lane_bcast(dl, jl);
                        } else {
                            int jh = (int)__ffsll((unsigned long long)t_mhi) - 1;
                            t_mhi &= t_mhi - 1;
                            j = 64 + jh;
                            dj = lane_bcast(dh, jh);
                        }
                        int cjj = (j & 7) << 2;
                        int base = j * 128 + (rlo ^ cjj);
                        float n_lo = fmaf(vsh[base], dj, s_lo);
                        float n_hi = fmaf(vsh[base + 64], dj, s_hi);
                        bool pl = (n_lo < aeps_lo) && (n_lo > -aeps_lo);
                        bool ph = (n_hi < aeps_hi) && (n_hi > -aeps_hi);
                        if (__ballot(pl && ph) == ~0ull) { judge = true; break; }
                    }
                }
            } else {
                // ---- parallel judge: lane tests candidates j=lane, lane+64.
                // s/aeps via uniform-address b128 reads (HW broadcast) instead
                // of readlanes; early-exit when every candidate already failed
                // (final judge provably false -> exact). m-accumulation order
                // unchanged -> identical judge boolean.
                float m1 = -1.0f, m2 = -1.0f;   // only the sign of max matters
                bool dead = false;
#pragma unroll
                for (int a = 0; a < 4; ++a) {
                    if (!dead) {
#pragma unroll
                        for (int c = 0; c < 8; ++c) {
                            const int i0 = a * 32 + c * 4;
                            const float* p1 = &vsh[Abase[c] + 32 * a];
                            float4 c1 = *(const float4*)p1;
                            float4 c2 = *(const float4*)(p1 + 8192);
                            float4 s4 = *(const float4*)&sstage[w][i0];   // uniform
                            float4 ae4 = *(const float4*)&aeps_arr[i0];   // uniform
#pragma unroll
                            for (int e = 0; e < 4; ++e) {
                                float sv = ((const float*)&s4)[e];
                                float ae = ((const float*)&ae4)[e];
                                float f1 = ((const float*)&c1)[e];
                                float f2 = ((const float*)&c2)[e];
                                m1 = fmaxf(m1, fabsf(fmaf(f1, dl, sv)) - ae);
                                m2 = fmaxf(m2, fabsf(fmaf(f2, dh, sv)) - ae);
                            }
                        }
                        if (a < 3) {
                            if ((__ballot(m1 < 0.0f) | __ballot(m2 < 0.0f)) == 0ull)
                                dead = true;   // all candidates failed already
                        }
                    }
                }
                judge = ((__ballot(m1 < 0.0f) | __ballot(m2 < 0.0f)) != 0ull);
            }

            if (judge) {
                // ---- Gauss-Seidel sweep (ascending j, violators only) ----
                uint64_t rem_lo = ~0ull, rem_hi = ~0ull;
                while (true) {
                    uint64_t m1b = __ballot((s_lo > a_lo) || (s_lo < -a_lo)) & rem_lo;
                    uint64_t m2b = __ballot((s_hi > a_hi) || (s_hi < -a_hi)) & rem_hi;
                    int j;
                    if (m1b) {
                        int jl = (int)__ffsll((unsigned long long)m1b) - 1;
                        j = jl;
                        rem_lo = (jl == 63) ? 0ull : (~0ull << (jl + 1));
                    } else if (m2b) {
                        int jh = (int)__ffsll((unsigned long long)m2b) - 1;
                        j = 64 + jh;
                        rem_lo = 0ull;
                        rem_hi = (jh == 63) ? 0ull : (~0ull << (jh + 1));
                    } else {
                        break;
                    }
                    float dl2 = (s_lo > a_lo) ? (a_lo - s_lo) * rvd_lo
                               : ((s_lo < -a_lo) ? (-a_lo - s_lo) * rvd_lo : 0.0f);
                    float dh2 = (s_hi > a_hi) ? (a_hi - s_hi) * rvd_hi
                               : ((s_hi < -a_hi) ? (-a_hi - s_hi) * rvd_hi : 0.0f);
                    float srcv = (j < 64) ? dl2 : dh2;
                    float dj = lane_bcast(srcv, j & 63);
                    if (lane == (j & 63)) {
                        if (j < 64) h_lo += dj; else h_hi += dj;
                    }
                    int cjj = (j & 7) << 2;
                    int base = j * 128 + (rlo ^ cjj);
                    s_lo = fmaf(vsh[base], dj, s_lo);
                    s_hi = fmaf(vsh[base + 64], dj, s_hi);
                }
            } else {
                // ---- bisection between pi_bar (s=0) and adj (s), s-space ----
                float hin_lo = tgt_lo, hin_hi = tgt_hi;
                float sin_lo = 0.0f, sin_hi = 0.0f;
                float hout_lo = h_lo, hout_hi = h_hi;
                float sout_lo = s_lo, sout_hi = s_hi;
                float hm_lo = 0.0f, hm_hi = 0.0f;
#pragma unroll
                for (int it = 0; it < 10; ++it) {
                    hm_lo = hin_lo + (hout_lo - hin_lo) * 0.5f;
                    hm_hi = hin_hi + (hout_hi - hin_hi) * 0.5f;
                    float sm_lo = sin_lo + (sout_lo - sin_lo) * 0.5f;
                    float sm_hi = sin_hi + (sout_hi - sin_hi) * 0.5f;
                    bool pl = (sm_lo <= aeps_lo) && (sm_lo >= -aeps_lo);
                    bool ph = (sm_hi <= aeps_hi) && (sm_hi >= -aeps_hi);
                    bool inside = (__ballot(pl && ph) == ~0ull);
                    if (inside) {
                        hin_lo = hm_lo; hin_hi = hm_hi;
                        sin_lo = sm_lo; sin_hi = sm_hi;
                    } else {
                        hout_lo = hm_lo; hout_hi = hm_hi;
                        sout_lo = sm_lo; sout_hi = sm_hi;
                    }
                }
                h_lo = hm_lo;
                h_hi = hm_hi;
            }
        }
        // else: no violators -> judge=1, sweep is a no-op, h unchanged

        out[rlo * T * B + t * B + b] = h_lo;
        out[rhi * T * B + t * B + b] = h_hi;
    }

    out[D * T * B + rlo * B + b] = h_lo;
    out[D * T * B + rhi * B + b] = h_hi;
}

extern "C" void kernel_launch(void* const* d_in, const int* in_sizes, int n_in,
                              void* d_out, int out_size, void* d_ws, size_t ws_size,
                              hipStream_t stream) {
    const float* input   = (const float*)d_in[0];
    const float* target  = (const float*)d_in[1];
    const float* returns = (const float*)d_in[2];
    // d_in[3] = hidden (unused by the reference)
    const float* W = (const float*)d_in[4];
    const float* b = (const float*)d_in[5];
    float* out = (float*)d_out;

    float* vT   = (float*)d_ws;            // 16384 floats
    float* vd   = vT + D * D;              // 128 floats
    float* absb = vd + D;                  // 128 floats

    prep_kernel<<<D, 64, 0, stream>>>(W, b, vT, vd, absb);
    rnn_kernel<<<B / 2, 128, 0, stream>>>(input, target, returns, vT, vd, absb, out);
}